// Round 4
// baseline (400.374 us; speedup 1.0000x reference)
//
#include <hip/hip_runtime.h>

#define NV 100000
#define NF 50000
#define NE 1000000
#define NBV 1563   // ceil(NV/64)
#define NBF 782    // ceil(NF/64)
// D = 128 throughout

typedef unsigned short ushort_t;
typedef unsigned int uint_t;
typedef __attribute__((ext_vector_type(8))) short bf16x8;   // 8 bf16 = 4 VGPRs
typedef __attribute__((ext_vector_type(4))) float f32x4;

__device__ inline ushort_t f2bf(float x) {
    union { float f; uint_t u; } c; c.f = x;
    uint_t r = c.u + 0x7fffu + ((c.u >> 16) & 1u);   // round-to-nearest-even
    return (ushort_t)(r >> 16);
}
__device__ inline float bf2f(uint_t h) {
    union { uint_t u; float f; } c; c.u = h << 16; return c.f;
}
__device__ inline uint_t pack2(float a, float b) {
    return (uint_t)f2bf(a) | ((uint_t)f2bf(b) << 16);
}
__device__ inline bf16x8 pack_frag(const float* p) {
    float4 lo = *(const float4*)p;
    float4 hi = *(const float4*)(p + 4);
    bf16x8 r;
    r[0] = (short)f2bf(lo.x); r[1] = (short)f2bf(lo.y);
    r[2] = (short)f2bf(lo.z); r[3] = (short)f2bf(lo.w);
    r[4] = (short)f2bf(hi.x); r[5] = (short)f2bf(hi.y);
    r[6] = (short)f2bf(hi.z); r[7] = (short)f2bf(hi.w);
    return r;
}

// -------------------- zero int array --------------------
__global__ __launch_bounds__(256) void zero_i(int* __restrict__ p, int n) {
    int i = blockIdx.x * 256 + threadIdx.x;
    if (i < n) p[i] = 0;
}

// -------------------- histogram of v_to_f (4 edges/thread) --------------------
__global__ __launch_bounds__(256) void hist_k(const int* __restrict__ vtf, int* __restrict__ deg) {
    int e4 = blockIdx.x * 256 + threadIdx.x;
    if (e4 < NE / 4) {
        int4 v = *(const int4*)(vtf + e4 * 4);
        atomicAdd(&deg[v.x], 1);
        atomicAdd(&deg[v.y], 1);
        atomicAdd(&deg[v.z], 1);
        atomicAdd(&deg[v.w], 1);
    }
}

// -------------------- scan pass 1: per-1024-chunk sums --------------------
__global__ __launch_bounds__(256) void scan_reduce(const int* __restrict__ deg, int* __restrict__ bsum) {
    __shared__ int s[256];
    int t = threadIdx.x, b = blockIdx.x;
    int base = b * 1024 + t * 4;
    int acc = 0;
#pragma unroll
    for (int j = 0; j < 4; j++) { int i = base + j; if (i < NV) acc += deg[i]; }
    s[t] = acc; __syncthreads();
    for (int off = 128; off > 0; off >>= 1) {
        if (t < off) s[t] += s[t + off];
        __syncthreads();
    }
    if (t == 0) bsum[b] = s[0];
}

// -------------------- scan pass 2: exclusive scan of block sums (1 block) ---------
__global__ __launch_bounds__(128) void scan_mid(int* __restrict__ bsum, int* __restrict__ offs, int nblk) {
    __shared__ int s[128];
    int t = threadIdx.x;
    int val = (t < nblk) ? bsum[t] : 0;
    s[t] = val; __syncthreads();
    for (int off = 1; off < 128; off <<= 1) {
        int x = (t >= off) ? s[t - off] : 0;
        __syncthreads();
        s[t] += x;
        __syncthreads();
    }
    if (t < nblk) bsum[t] = s[t] - val;   // exclusive block offsets
    if (t == 0) offs[NV] = NE;
}

// -------------------- scan pass 3: full exclusive scan; offs + cursor --------------
__global__ __launch_bounds__(256) void scan_final(int* __restrict__ deg, const int* __restrict__ bsum,
                                                  int* __restrict__ offs) {
    __shared__ int s[256];
    int t = threadIdx.x, b = blockIdx.x;
    int base = b * 1024 + t * 4;
    int v[4];
#pragma unroll
    for (int j = 0; j < 4; j++) { int i = base + j; v[j] = (i < NV) ? deg[i] : 0; }
    int l = v[0] + v[1] + v[2] + v[3];
    s[t] = l; __syncthreads();
    for (int off = 1; off < 256; off <<= 1) {
        int x = (t >= off) ? s[t - off] : 0;
        __syncthreads();
        s[t] += x;
        __syncthreads();
    }
    int run = bsum[b] + s[t] - l;
#pragma unroll
    for (int j = 0; j < 4; j++) {
        int i = base + j;
        if (i < NV) { offs[i] = run; deg[i] = run; }  // deg becomes the scatter cursor
        run += v[j];
    }
}

// -------------------- scatter f-indices into CSR slots (2 edges/thread) ------------
__global__ __launch_bounds__(256) void scatter_k(const int* __restrict__ vtf, const int* __restrict__ ftv,
                                                 int* __restrict__ cursor, ushort_t* __restrict__ sf) {
    int e2 = blockIdx.x * 256 + threadIdx.x;
    if (e2 < NE / 2) {
        int2 v = *(const int2*)(vtf + e2 * 2);
        int2 f = *(const int2*)(ftv + e2 * 2);
        int p0 = atomicAdd(&cursor[v.x], 1);
        sf[p0] = (ushort_t)f.x;
        int p1 = atomicAdd(&cursor[v.y], 1);
        sf[p1] = (ushort_t)f.y;
    }
}

// ---------- prep: rewrite 4 x [128x128] fp32 weight halves into bf16 B-fragment layout ----
// B-frag element (k,n): kc=k>>5, quad=(k&31)>>3, j=k&7, ct=n>>4, lane=(n&15)+16*quad
// storage: frag[mat][ ((kc*8+ct)*64 + lane)*8 + j ]
__global__ __launch_bounds__(256) void prep_w(const float* __restrict__ Wm, const float* __restrict__ Wc,
                                              ushort_t* __restrict__ frag) {
    int t = blockIdx.x * 256 + threadIdx.x;     // 65536 threads
    int mat = t >> 14;
    int idx = t & 16383;
    int k = idx >> 7, n = idx & 127;
    const float* src = (mat < 2) ? (Wm + (size_t)mat * 16384) : (Wc + (size_t)(mat - 2) * 16384);
    float v = src[(size_t)k * 128 + n];
    int kc = k >> 5, kk = k & 31, quad = kk >> 3, j = kk & 7;
    int ct = n >> 4, np = n & 15, lane = np + 16 * quad;
    frag[(size_t)mat * 16384 + (size_t)((kc * 8 + ct) * 64 + lane) * 8 + j] = f2bf(v);
}

// ---------- MFMA GEMM: u = bf16(V@Wm_top + b_msg); w = bf16(F@Wm_bot) — one grid ---------
// block = 4 waves, wave = 16 rows x 128 cols, no LDS.
__global__ __launch_bounds__(256) void gemm_msg(const float* __restrict__ V,
                                                const float* __restrict__ F,
                                                const ushort_t* __restrict__ wfm,
                                                const float* __restrict__ bias,
                                                ushort_t* __restrict__ u,
                                                ushort_t* __restrict__ w) {
    const float* A; const ushort_t* wf; ushort_t* C; const float* bs; int M, r0;
    if (blockIdx.x < NBV) { A = V; wf = wfm;         C = u; bs = bias;    M = NV; r0 = blockIdx.x * 64; }
    else                  { A = F; wf = wfm + 16384; C = w; bs = nullptr; M = NF; r0 = (blockIdx.x - NBV) * 64; }

    const int wv = threadIdx.x >> 6;
    const int lane = threadIdx.x & 63;
    const int quad = lane >> 4, np = lane & 15;
    const int arow = r0 + wv * 16 + np;

    f32x4 acc[8];
#pragma unroll
    for (int ct = 0; ct < 8; ct++) acc[ct] = (f32x4){0.f, 0.f, 0.f, 0.f};

#pragma unroll
    for (int kc = 0; kc < 4; kc++) {
        bf16x8 a = {0, 0, 0, 0, 0, 0, 0, 0};
        if (arow < M) a = pack_frag(A + (size_t)arow * 128 + kc * 32 + quad * 8);
        const ushort_t* wp = wf + (size_t)(kc * 8 * 64 + lane) * 8;
#pragma unroll
        for (int ct = 0; ct < 8; ct++) {
            bf16x8 b = *(const bf16x8*)(wp + ct * 512);
            acc[ct] = __builtin_amdgcn_mfma_f32_16x16x32_bf16(a, b, acc[ct], 0, 0, 0);
        }
    }

    const int orow0 = r0 + wv * 16 + quad * 4;   // D row = quad*4 + reg
#pragma unroll
    for (int ct = 0; ct < 8; ct++) {
        int col = ct * 16 + np;
        float bb = bs ? bs[col] : 0.f;
#pragma unroll
        for (int r = 0; r < 4; r++) {
            int orow = orow0 + r;
            if (orow < M) C[(size_t)orow * 128 + col] = f2bf(acc[ct][r] + bb);
        }
    }
}

// ---------- fused: aggregate 64 vars into LDS, then OUT = V + relu(V@W1 + aggr@W2 + b) ---
// Phase 1: wave wv aggregates vars r0+wv*16..+15; lane owns col pair (2l,2l+1); MLP=4.
// Phase 2: K=256 MFMA; kc0..3 A from V (fp32->bf16), kc4..7 A from LDS aggr tile.
__global__ __launch_bounds__(256) void agg_final(const float* __restrict__ V,
                                                 const uint_t* __restrict__ u32,
                                                 const uint_t* __restrict__ w32,
                                                 const int* __restrict__ offs,
                                                 const ushort_t* __restrict__ sf,
                                                 const ushort_t* __restrict__ wfc,
                                                 const float* __restrict__ bias,
                                                 float* __restrict__ OUT) {
    __shared__ uint_t sAg[64][68];    // 64 rows x 64 uints (+4 pad): 2-way max on all patterns

    const int wv = threadIdx.x >> 6;
    const int lane = threadIdx.x & 63;
    const int quad = lane >> 4, np = lane & 15;
    const int r0 = blockIdx.x * 64;

    // ---- phase 1: aggregate ----
    for (int s = 0; s < 16; s++) {
        int v = r0 + wv * 16 + s;
        float a0 = 0.f, a1 = 0.f, b0 = 0.f, b1 = 0.f, c0 = 0.f, c1 = 0.f, d0 = 0.f, d1 = 0.f;
        if (v < NV) {
            uint_t upk = u32[(size_t)v * 64 + lane];
            float u0 = bf2f(upk & 0xffffu), u1 = bf2f(upk >> 16);
            int i = offs[v], i1 = offs[v + 1];
            for (; i + 4 <= i1; i += 4) {
                int f0 = sf[i], f1 = sf[i + 1], f2 = sf[i + 2], f3 = sf[i + 3];
                uint_t p0 = w32[(size_t)f0 * 64 + lane];
                uint_t p1 = w32[(size_t)f1 * 64 + lane];
                uint_t p2 = w32[(size_t)f2 * 64 + lane];
                uint_t p3 = w32[(size_t)f3 * 64 + lane];
                a0 += fmaxf(u0 + bf2f(p0 & 0xffffu), 0.f);
                a1 += fmaxf(u1 + bf2f(p0 >> 16), 0.f);
                b0 += fmaxf(u0 + bf2f(p1 & 0xffffu), 0.f);
                b1 += fmaxf(u1 + bf2f(p1 >> 16), 0.f);
                c0 += fmaxf(u0 + bf2f(p2 & 0xffffu), 0.f);
                c1 += fmaxf(u1 + bf2f(p2 >> 16), 0.f);
                d0 += fmaxf(u0 + bf2f(p3 & 0xffffu), 0.f);
                d1 += fmaxf(u1 + bf2f(p3 >> 16), 0.f);
            }
            for (; i < i1; i++) {
                uint_t p0 = w32[(size_t)sf[i] * 64 + lane];
                a0 += fmaxf(u0 + bf2f(p0 & 0xffffu), 0.f);
                a1 += fmaxf(u1 + bf2f(p0 >> 16), 0.f);
            }
        }
        sAg[wv * 16 + s][lane] = pack2((a0 + b0) + (c0 + d0), (a1 + b1) + (c1 + d1));
    }
    __syncthreads();

    // ---- phase 2: MFMA ----
    const int arow = r0 + wv * 16 + np;
    f32x4 acc[8];
#pragma unroll
    for (int ct = 0; ct < 8; ct++) acc[ct] = (f32x4){0.f, 0.f, 0.f, 0.f};

#pragma unroll
    for (int kc = 0; kc < 8; kc++) {
        bf16x8 a;
        if (kc < 4) {
            a = (bf16x8){0, 0, 0, 0, 0, 0, 0, 0};
            if (arow < NV) a = pack_frag(V + (size_t)arow * 128 + kc * 32 + quad * 8);
        } else {
            a = *(const bf16x8*)&sAg[wv * 16 + np][(kc - 4) * 16 + quad * 4];
        }
        const ushort_t* wp = wfc + (size_t)(kc >= 4 ? 16384 : 0)
                                 + (size_t)((kc & 3) * 8 * 64 + lane) * 8;
#pragma unroll
        for (int ct = 0; ct < 8; ct++) {
            bf16x8 b = *(const bf16x8*)(wp + ct * 512);
            acc[ct] = __builtin_amdgcn_mfma_f32_16x16x32_bf16(a, b, acc[ct], 0, 0, 0);
        }
    }

    const int orow0 = r0 + wv * 16 + quad * 4;
#pragma unroll
    for (int ct = 0; ct < 8; ct++) {
        int col = ct * 16 + np;
        float bb = bias[col];
#pragma unroll
        for (int r = 0; r < 4; r++) {
            int orow = orow0 + r;
            if (orow < NV) {
                float v = V[(size_t)orow * 128 + col];
                OUT[(size_t)orow * 128 + col] = v + fmaxf(acc[ct][r] + bb, 0.f);
            }
        }
    }
}

extern "C" void kernel_launch(void* const* d_in, const int* in_sizes, int n_in,
                              void* d_out, int out_size, void* d_ws, size_t ws_size,
                              hipStream_t stream) {
    const float* variables = (const float*)d_in[0];   // [100000, 128]
    const float* factors   = (const float*)d_in[1];   // [50000, 128]
    const int*   v_to_f    = (const int*)d_in[2];     // [1e6]
    const int*   f_to_v    = (const int*)d_in[3];     // [1e6]
    // d_in[4] edge_attr: forward uses zeros_like -> last row of W_msg contributes nothing
    const float* W_msg     = (const float*)d_in[5];   // [257, 128]
    const float* b_msg     = (const float*)d_in[6];   // [128]
    const float* W_comb    = (const float*)d_in[7];   // [256, 128]
    const float* b_comb    = (const float*)d_in[8];   // [128]
    float* out = (float*)d_out;                       // [100000, 128]

    // workspace layout (~41.5 MB)
    ushort_t* wfrag = (ushort_t*)d_ws;                 // 4 x 16384 bf16 = 128 KB
    ushort_t* u     = wfrag + 4 * 16384;               // [NV*128] bf16
    ushort_t* w     = u + (size_t)NV * 128;            // [NF*128] bf16
    ushort_t* sf    = w + (size_t)NF * 128;            // [NE] uint16 factor ids
    int*      deg   = (int*)(sf + NE);                 // [NV]
    int*      offs  = deg + NV;                        // [NV+1]
    int*      bsum  = offs + NV + 1;                   // [128]

    const int NBLK = (NV + 1023) / 1024;               // 98

    // ---- weight fragments (independent of everything) ----
    prep_w<<<256, 256, 0, stream>>>(W_msg, W_comb, wfrag);

    // ---- CSR build ----
    zero_i<<<(NV + 255) / 256, 256, 0, stream>>>(deg, NV);
    hist_k<<<(NE / 4 + 255) / 256, 256, 0, stream>>>(v_to_f, deg);
    scan_reduce<<<NBLK, 256, 0, stream>>>(deg, bsum);
    scan_mid<<<1, 128, 0, stream>>>(bsum, offs, NBLK);
    scan_final<<<NBLK, 256, 0, stream>>>(deg, bsum, offs);
    scatter_k<<<(NE / 2 + 255) / 256, 256, 0, stream>>>(v_to_f, f_to_v, deg, sf);

    // ---- u = bf16(V @ Wm_top + b_msg), w = bf16(F @ Wm_bot), single grid ----
    gemm_msg<<<NBV + NBF, 256, 0, stream>>>(variables, factors, wfrag, b_msg, u, w);

    // ---- fused aggregate + final GEMM ----
    agg_final<<<NBV, 256, 0, stream>>>(variables, (const uint_t*)u, (const uint_t*)w,
                                       offs, sf, wfrag + 2 * 16384, b_comb, out);
}

// Round 5
// 360.436 us; speedup vs baseline: 1.1108x; 1.1108x over previous
//
#include <hip/hip_runtime.h>

#define NV 100000
#define NF 50000
#define NE 1000000
#define NBV 1563   // ceil(NV/64)
#define NBF 782    // ceil(NF/64)
// D = 128 throughout

typedef unsigned short ushort_t;
typedef unsigned int uint_t;
typedef __attribute__((ext_vector_type(8))) short bf16x8;   // 8 bf16 = 4 VGPRs
typedef __attribute__((ext_vector_type(4))) float f32x4;

// Permuted storage layout for u/w/aggr rows (128 bf16 = 64 packed uints):
//   packed uint j holds actual cols ( (j&15)+32*(j>>4) , same+16 )
//   i.e. bf16 position p maps to col pi(p) = ((p>>1)&15) + 32*((p>>1)>>4) + 16*(p&1)
// Consumers: aggregate is elementwise (layout-agnostic); gemm_final's W_comb-bottom
// fragment has its k-rows permuted by pi in prep_w, making the GEMM invariant.

__device__ inline ushort_t f2bf(float x) {
    union { float f; uint_t u; } c; c.f = x;
    uint_t r = c.u + 0x7fffu + ((c.u >> 16) & 1u);   // round-to-nearest-even
    return (ushort_t)(r >> 16);
}
__device__ inline float bf2f(uint_t h) {
    union { uint_t u; float f; } c; c.u = h << 16; return c.f;
}
__device__ inline uint_t pack2(float a, float b) {
    return (uint_t)f2bf(a) | ((uint_t)f2bf(b) << 16);
}
__device__ inline bf16x8 pack_frag(const float* p) {
    float4 lo = *(const float4*)p;
    float4 hi = *(const float4*)(p + 4);
    bf16x8 r;
    r[0] = (short)f2bf(lo.x); r[1] = (short)f2bf(lo.y);
    r[2] = (short)f2bf(lo.z); r[3] = (short)f2bf(lo.w);
    r[4] = (short)f2bf(hi.x); r[5] = (short)f2bf(hi.y);
    r[6] = (short)f2bf(hi.z); r[7] = (short)f2bf(hi.w);
    return r;
}

// -------------------- histogram of v_to_f (4 edges/thread, fire-and-forget) ---------
__global__ __launch_bounds__(256) void hist_k(const int* __restrict__ vtf, int* __restrict__ deg) {
    int e4 = blockIdx.x * 256 + threadIdx.x;
    if (e4 < NE / 4) {
        int4 v = *(const int4*)(vtf + e4 * 4);
        atomicAdd(&deg[v.x], 1);
        atomicAdd(&deg[v.y], 1);
        atomicAdd(&deg[v.z], 1);
        atomicAdd(&deg[v.w], 1);
    }
}

// -------------------- scan pass 1: per-1024-chunk sums --------------------
__global__ __launch_bounds__(256) void scan_reduce(const int* __restrict__ deg, int* __restrict__ bsum) {
    __shared__ int s[256];
    int t = threadIdx.x, b = blockIdx.x;
    int base = b * 1024 + t * 4;
    int acc = 0;
#pragma unroll
    for (int j = 0; j < 4; j++) { int i = base + j; if (i < NV) acc += deg[i]; }
    s[t] = acc; __syncthreads();
    for (int off = 128; off > 0; off >>= 1) {
        if (t < off) s[t] += s[t + off];
        __syncthreads();
    }
    if (t == 0) bsum[b] = s[0];
}

// -------------------- scan pass 2: exclusive scan of block sums (1 block) ---------
__global__ __launch_bounds__(128) void scan_mid(int* __restrict__ bsum, int* __restrict__ offs, int nblk) {
    __shared__ int s[128];
    int t = threadIdx.x;
    int val = (t < nblk) ? bsum[t] : 0;
    s[t] = val; __syncthreads();
    for (int off = 1; off < 128; off <<= 1) {
        int x = (t >= off) ? s[t - off] : 0;
        __syncthreads();
        s[t] += x;
        __syncthreads();
    }
    if (t < nblk) bsum[t] = s[t] - val;   // exclusive block offsets
    if (t == 0) offs[NV] = NE;
}

// -------------------- scan pass 3: full exclusive scan; offs + cursor --------------
__global__ __launch_bounds__(256) void scan_final(int* __restrict__ deg, const int* __restrict__ bsum,
                                                  int* __restrict__ offs) {
    __shared__ int s[256];
    int t = threadIdx.x, b = blockIdx.x;
    int base = b * 1024 + t * 4;
    int v[4];
#pragma unroll
    for (int j = 0; j < 4; j++) { int i = base + j; v[j] = (i < NV) ? deg[i] : 0; }
    int l = v[0] + v[1] + v[2] + v[3];
    s[t] = l; __syncthreads();
    for (int off = 1; off < 256; off <<= 1) {
        int x = (t >= off) ? s[t - off] : 0;
        __syncthreads();
        s[t] += x;
        __syncthreads();
    }
    int run = bsum[b] + s[t] - l;
#pragma unroll
    for (int j = 0; j < 4; j++) {
        int i = base + j;
        if (i < NV) { offs[i] = run; deg[i] = run; }  // deg becomes the scatter cursor
        run += v[j];
    }
}

// -------------------- scatter f-indices into CSR slots (2 edges/thread) ------------
__global__ __launch_bounds__(256) void scatter_k(const int* __restrict__ vtf, const int* __restrict__ ftv,
                                                 int* __restrict__ cursor, ushort_t* __restrict__ sf) {
    int e2 = blockIdx.x * 256 + threadIdx.x;
    if (e2 < NE / 2) {
        int2 v = *(const int2*)(vtf + e2 * 2);
        int2 f = *(const int2*)(ftv + e2 * 2);
        int p0 = atomicAdd(&cursor[v.x], 1);
        sf[p0] = (ushort_t)f.x;
        int p1 = atomicAdd(&cursor[v.y], 1);
        sf[p1] = (ushort_t)f.y;
    }
}

// ---------- prep: rewrite 4 x [128x128] fp32 weight halves into bf16 B-fragment layout ----
// B-frag element (k,n): kc=k>>5, quad=(k&31)>>3, j=k&7, ct=n>>4, lane=(n&15)+16*quad
// storage: frag[mat][ ((kc*8+ct)*64 + lane)*8 + j ]
// mat 3 (W_comb bottom): source row is pi(k) to match the permuted aggr layout.
__global__ __launch_bounds__(256) void prep_w(const float* __restrict__ Wm, const float* __restrict__ Wc,
                                              ushort_t* __restrict__ frag) {
    int t = blockIdx.x * 256 + threadIdx.x;     // 65536 threads
    int mat = t >> 14;
    int idx = t & 16383;
    int k = idx >> 7, n = idx & 127;
    int srck = k;
    if (mat == 3) {
        int j = k >> 1;
        srck = (j & 15) + 32 * (j >> 4) + 16 * (k & 1);   // pi(k)
    }
    const float* src = (mat < 2) ? (Wm + (size_t)mat * 16384) : (Wc + (size_t)(mat - 2) * 16384);
    float v = src[(size_t)srck * 128 + n];
    int kc = k >> 5, kk = k & 31, quad = kk >> 3, j = kk & 7;
    int ct = n >> 4, np = n & 15, lane = np + 16 * quad;
    frag[(size_t)mat * 16384 + (size_t)((kc * 8 + ct) * 64 + lane) * 8 + j] = f2bf(v);
}

// ---------- MFMA GEMM: u = bf16(V@Wm_top + b_msg); w = bf16(F@Wm_bot) — one grid ---------
// block = 4 waves, wave = 16 rows x 128 cols, no LDS. Output stored in permuted packed
// layout: uint j = g*16+np holds cols (np+32g, np+32g+16) = acc[2g], acc[2g+1].
__global__ __launch_bounds__(256) void gemm_msg(const float* __restrict__ V,
                                                const float* __restrict__ F,
                                                const ushort_t* __restrict__ wfm,
                                                const float* __restrict__ bias,
                                                uint_t* __restrict__ u,
                                                uint_t* __restrict__ w) {
    const float* A; const ushort_t* wf; uint_t* C; const float* bs; int M, r0;
    if (blockIdx.x < NBV) { A = V; wf = wfm;         C = u; bs = bias;    M = NV; r0 = blockIdx.x * 64; }
    else                  { A = F; wf = wfm + 16384; C = w; bs = nullptr; M = NF; r0 = (blockIdx.x - NBV) * 64; }

    const int wv = threadIdx.x >> 6;
    const int lane = threadIdx.x & 63;
    const int quad = lane >> 4, np = lane & 15;
    const int arow = r0 + wv * 16 + np;

    f32x4 acc[8];
#pragma unroll
    for (int ct = 0; ct < 8; ct++) acc[ct] = (f32x4){0.f, 0.f, 0.f, 0.f};

#pragma unroll
    for (int kc = 0; kc < 4; kc++) {
        bf16x8 a = {0, 0, 0, 0, 0, 0, 0, 0};
        if (arow < M) a = pack_frag(A + (size_t)arow * 128 + kc * 32 + quad * 8);
        const ushort_t* wp = wf + (size_t)(kc * 8 * 64 + lane) * 8;
#pragma unroll
        for (int ct = 0; ct < 8; ct++) {
            bf16x8 b = *(const bf16x8*)(wp + ct * 512);
            acc[ct] = __builtin_amdgcn_mfma_f32_16x16x32_bf16(a, b, acc[ct], 0, 0, 0);
        }
    }

#pragma unroll
    for (int g = 0; g < 4; g++) {
        float bb0 = bs ? bs[np + 32 * g] : 0.f;
        float bb1 = bs ? bs[np + 32 * g + 16] : 0.f;
#pragma unroll
        for (int r = 0; r < 4; r++) {
            int orow = r0 + wv * 16 + quad * 4 + r;   // D row = quad*4 + reg
            if (orow < M)
                C[(size_t)orow * 64 + g * 16 + np] = pack2(acc[2 * g][r] + bb0,
                                                           acc[2 * g + 1][r] + bb1);
        }
    }
}

// ---------- CSR segmented sum (permuted packed layout), one wave/variable, MLP=8 ---------
// Constant-shape inner loop: 8 clamped sf loads + 8 independent row gathers per round,
// contributions predicated. deg~10 -> ~1.3 rounds.
__global__ __launch_bounds__(256) void aggregate(const uint_t* __restrict__ u32,
                                                 const uint_t* __restrict__ w32,
                                                 const int* __restrict__ offs,
                                                 const ushort_t* __restrict__ sf,
                                                 uint_t* __restrict__ aggr32) {
    int v = (blockIdx.x * 256 + threadIdx.x) >> 6;
    int lane = threadIdx.x & 63;
    if (v >= NV) return;
    int i0 = offs[v], i1 = offs[v + 1];
    uint_t upk = u32[(size_t)v * 64 + lane];
    float u0 = bf2f(upk & 0xffffu), u1 = bf2f(upk >> 16);
    float ax[8], ay[8];
#pragma unroll
    for (int j = 0; j < 8; j++) { ax[j] = 0.f; ay[j] = 0.f; }
    for (int i = i0; i < i1; i += 8) {
        int f[8];
#pragma unroll
        for (int j = 0; j < 8; j++) {
            int idx = i + j; if (idx > i1 - 1) idx = i1 - 1;
            f[j] = sf[idx];
        }
        uint_t p[8];
#pragma unroll
        for (int j = 0; j < 8; j++) p[j] = w32[(size_t)f[j] * 64 + lane];
#pragma unroll
        for (int j = 0; j < 8; j++) {
            if (i + j < i1) {
                ax[j] += fmaxf(u0 + bf2f(p[j] & 0xffffu), 0.f);
                ay[j] += fmaxf(u1 + bf2f(p[j] >> 16), 0.f);
            }
        }
    }
    float sx = ((ax[0] + ax[1]) + (ax[2] + ax[3])) + ((ax[4] + ax[5]) + (ax[6] + ax[7]));
    float sy = ((ay[0] + ay[1]) + (ay[2] + ay[3])) + ((ay[4] + ay[5]) + (ay[6] + ay[7]));
    aggr32[(size_t)v * 64 + lane] = pack2(sx, sy);
}

// ---------- MFMA final: OUT_fp32 = V + relu(V@Wc_top + aggr@Wc_bot + bias) ---------------
// K = 256: kc 0..3 from V (fp32->bf16), kc 4..7 from aggr (permuted bf16; W-frag rows
// were permuted to match in prep_w).
__global__ __launch_bounds__(256) void gemm_final(const float* __restrict__ V,
                                                  const ushort_t* __restrict__ aggr,
                                                  const ushort_t* __restrict__ wfc,
                                                  const float* __restrict__ bias,
                                                  float* __restrict__ OUT, int M) {
    const int wv = threadIdx.x >> 6;
    const int lane = threadIdx.x & 63;
    const int quad = lane >> 4, np = lane & 15;
    const int arow = blockIdx.x * 64 + wv * 16 + np;

    f32x4 acc[8];
#pragma unroll
    for (int ct = 0; ct < 8; ct++) acc[ct] = (f32x4){0.f, 0.f, 0.f, 0.f};

#pragma unroll
    for (int kc = 0; kc < 8; kc++) {
        bf16x8 a;
        if (kc < 4) {
            a = (bf16x8){0, 0, 0, 0, 0, 0, 0, 0};
            if (arow < M) a = pack_frag(V + (size_t)arow * 128 + kc * 32 + quad * 8);
        } else {
            a = (bf16x8){0, 0, 0, 0, 0, 0, 0, 0};
            if (arow < M) a = *(const bf16x8*)(aggr + (size_t)arow * 128 + (kc - 4) * 32 + quad * 8);
        }
        const ushort_t* wp = wfc + (size_t)(kc >= 4 ? 16384 : 0)
                                 + (size_t)((kc & 3) * 8 * 64 + lane) * 8;
#pragma unroll
        for (int ct = 0; ct < 8; ct++) {
            bf16x8 b = *(const bf16x8*)(wp + ct * 512);
            acc[ct] = __builtin_amdgcn_mfma_f32_16x16x32_bf16(a, b, acc[ct], 0, 0, 0);
        }
    }

    const int orow0 = blockIdx.x * 64 + wv * 16 + quad * 4;
#pragma unroll
    for (int ct = 0; ct < 8; ct++) {
        int col = ct * 16 + np;
        float bb = bias[col];
#pragma unroll
        for (int r = 0; r < 4; r++) {
            int orow = orow0 + r;
            if (orow < M) {
                float v = V[(size_t)orow * 128 + col];
                OUT[(size_t)orow * 128 + col] = v + fmaxf(acc[ct][r] + bb, 0.f);
            }
        }
    }
}

extern "C" void kernel_launch(void* const* d_in, const int* in_sizes, int n_in,
                              void* d_out, int out_size, void* d_ws, size_t ws_size,
                              hipStream_t stream) {
    const float* variables = (const float*)d_in[0];   // [100000, 128]
    const float* factors   = (const float*)d_in[1];   // [50000, 128]
    const int*   v_to_f    = (const int*)d_in[2];     // [1e6]
    const int*   f_to_v    = (const int*)d_in[3];     // [1e6]
    // d_in[4] edge_attr: forward uses zeros_like -> last row of W_msg contributes nothing
    const float* W_msg     = (const float*)d_in[5];   // [257, 128]
    const float* b_msg     = (const float*)d_in[6];   // [128]
    const float* W_comb    = (const float*)d_in[7];   // [256, 128]
    const float* b_comb    = (const float*)d_in[8];   // [128]
    float* out = (float*)d_out;                       // [100000, 128]

    // workspace layout (~41.5 MB)
    ushort_t* wfrag = (ushort_t*)d_ws;                 // 4 x 16384 bf16 = 128 KB
    uint_t*   u     = (uint_t*)(wfrag + 4 * 16384);    // [NV*64] packed bf16 pairs
    uint_t*   w     = u + (size_t)NV * 64;             // [NF*64] packed bf16 pairs
    uint_t*   aggr  = w + (size_t)NF * 64;             // [NV*64] packed bf16 pairs
    ushort_t* sf    = (ushort_t*)(aggr + (size_t)NV * 64);  // [NE] uint16 factor ids
    int*      deg   = (int*)(sf + NE);                 // [NV]
    int*      offs  = deg + NV;                        // [NV+1]
    int*      bsum  = offs + NV + 1;                   // [128]

    const int NBLK = (NV + 1023) / 1024;               // 98

    // ---- weight fragments (independent of everything) ----
    prep_w<<<256, 256, 0, stream>>>(W_msg, W_comb, wfrag);

    // ---- CSR build ----
    hipMemsetAsync(deg, 0, (size_t)NV * sizeof(int), stream);
    hist_k<<<(NE / 4 + 255) / 256, 256, 0, stream>>>(v_to_f, deg);
    scan_reduce<<<NBLK, 256, 0, stream>>>(deg, bsum);
    scan_mid<<<1, 128, 0, stream>>>(bsum, offs, NBLK);
    scan_final<<<NBLK, 256, 0, stream>>>(deg, bsum, offs);
    scatter_k<<<(NE / 2 + 255) / 256, 256, 0, stream>>>(v_to_f, f_to_v, deg, sf);

    // ---- u = bf16(V @ Wm_top + b_msg), w = bf16(F @ Wm_bot), single grid ----
    gemm_msg<<<NBV + NBF, 256, 0, stream>>>(variables, factors, wfrag, b_msg, u, w);

    // ---- segmented sum -> aggr (packed bf16) ----
    aggregate<<<(NV * 64) / 256, 256, 0, stream>>>(u, w, offs, sf, aggr);

    // ---- OUT = V + relu(V@Wc_top + aggr@Wc_bot + b_comb) ----
    gemm_final<<<NBV, 256, 0, stream>>>(variables, (const ushort_t*)aggr, wfrag + 2 * 16384,
                                        b_comb, out, NV);
}